// Round 1
// baseline (25.750 us; speedup 1.0000x reference)
//
#include <hip/hip_runtime.h>

// QuantizedEmbedding: out[t, d] = (qweight[input[t], d] - zeros[input[t]]) * scales[input[t]]
// B*S = 16384 tokens, DIM = 1024, VOCAB = 128000. Output fp32.
// Memory-bound gather: 64 MiB read (gathered rows) + 64 MiB write.

constexpr int DIM = 1024;

__global__ __launch_bounds__(256) void qembed_kernel(
    const int*   __restrict__ input,    // [NTOK] row indices
    const int*   __restrict__ qweight,  // [VOCAB, DIM] codes in [0,256)
    const float* __restrict__ scales,   // [VOCAB]
    const float* __restrict__ zeros,    // [VOCAB]
    float*       __restrict__ out,      // [NTOK, DIM]
    int ntok)
{
    const int tok = blockIdx.x;
    if (tok >= ntok) return;

    const int row = input[tok];              // block-uniform -> scalar load
    const float scale = scales[row];
    const float zero  = zeros[row];

    // DIM=1024 -> 256 int4 chunks per row; one chunk per thread.
    const int4* qrow = reinterpret_cast<const int4*>(qweight + (long long)row * DIM);
    float4*     orow = reinterpret_cast<float4*>(out + (long long)tok * DIM);

    const int t = threadIdx.x;               // 0..255
    int4 q = qrow[t];                        // 16B coalesced load
    float4 o;
    o.x = ((float)q.x - zero) * scale;
    o.y = ((float)q.y - zero) * scale;
    o.z = ((float)q.z - zero) * scale;
    o.w = ((float)q.w - zero) * scale;
    orow[t] = o;                             // 16B coalesced store
}

extern "C" void kernel_launch(void* const* d_in, const int* in_sizes, int n_in,
                              void* d_out, int out_size, void* d_ws, size_t ws_size,
                              hipStream_t stream) {
    const int*   input   = (const int*)d_in[0];    // [B*S] int32 indices
    const int*   qweight = (const int*)d_in[1];    // [VOCAB*DIM] int32 codes
    const float* scales  = (const float*)d_in[2];  // [VOCAB]
    const float* zeros   = (const float*)d_in[3];  // [VOCAB]
    float*       out     = (float*)d_out;          // [B*S*DIM] fp32

    const int ntok = in_sizes[0];                  // 16384
    dim3 grid(ntok);
    dim3 block(256);
    qembed_kernel<<<grid, block, 0, stream>>>(input, qweight, scales, zeros, out, ntok);
}